// Round 8
// baseline (297.243 us; speedup 1.0000x reference)
//
#include <hip/hip_runtime.h>
#include <hip/hip_bf16.h>

// Problem constants (from reference)
#define N_PFAS 20000
#define N_GW   100000
#define N_SW   20000
#define N_SEG  160000          // GW[0,100k) GP[100k,120k) SP[120k,140k) PS[140k,160k)
#define BASE_GW 0
#define BASE_GP 100000
#define BASE_SP 120000
#define BASE_PS 140000
#define NBIN 1250              // 160000 / 128 exactly (bin = 128 dst nodes)
#define NB_FILL 512            // chunk count (count/fill blocks)
#define SORT_CAP 12288         // LDS staging (max real bin ~10.3k; 48KB)
#define STAGE_CAP 8192         // fill_stage per-chunk LDS (CH = 7813)
#define N_XROW 140000          // xp 20000 | xg 100000 | xs 20000 packed rows
#define N_GPQ 156              // GP-dominant bins: 781..936
#define N_OTQ 1094             // other bins: 0..780 and 937..1249

typedef __attribute__((ext_vector_type(8))) short short8;   // 8 bf16 (4 VGPRs)
typedef __attribute__((ext_vector_type(4))) float f32x4;    // MFMA C/D frag
typedef __attribute__((ext_vector_type(2))) float f32x2;

__device__ __forceinline__ unsigned short f2bf(float f) {
    union { float f; unsigned int u; } v;
    v.f = f;
    unsigned int u = v.u;
    unsigned int r = (u + 0x7fffu + ((u >> 16) & 1u)) >> 16;  // RNE
    return (unsigned short)r;
}

// ---- fp8 encode/decode: HW e4m3 converters if available, else e5m2 ----
#if __has_builtin(__builtin_amdgcn_cvt_pk_f32_fp8) && __has_builtin(__builtin_amdgcn_cvt_pk_fp8_f32)
#define FP8_HW 1
__device__ __forceinline__ unsigned int enc_fp8x4(float4 v) {
    int r = __builtin_amdgcn_cvt_pk_fp8_f32(v.x, v.y, 0, false);
    r = __builtin_amdgcn_cvt_pk_fp8_f32(v.z, v.w, r, true);
    return (unsigned int)r;
}
__device__ __forceinline__ void dec_fp8x4v(unsigned int u, f32x2& lo, f32x2& hi) {
    lo = __builtin_amdgcn_cvt_pk_f32_fp8(u, false);
    hi = __builtin_amdgcn_cvt_pk_f32_fp8(u, true);
}
#else
// e5m2 = top byte of IEEE f16. Encode: f32->f16 (RNE) then RNE-round top byte.
__device__ __forceinline__ unsigned char enc1_e5m2(float f) {
    union { unsigned short u; _Float16 h; } cv;
    cv.h = (_Float16)f;
    unsigned int u = cv.u;
    unsigned int r = (u + 0x7Fu + ((u >> 8) & 1u)) >> 8;
    return (unsigned char)(r > 255u ? 255u : r);
}
__device__ __forceinline__ unsigned int enc_fp8x4(float4 v) {
    return (unsigned int)enc1_e5m2(v.x) | ((unsigned int)enc1_e5m2(v.y) << 8)
         | ((unsigned int)enc1_e5m2(v.z) << 16) | ((unsigned int)enc1_e5m2(v.w) << 24);
}
__device__ __forceinline__ float dec1_e5m2(unsigned int b) {
    union { unsigned short u; _Float16 h; } cv;
    cv.u = (unsigned short)(b << 8);
    return (float)cv.h;
}
__device__ __forceinline__ void dec_fp8x4v(unsigned int u, f32x2& lo, f32x2& hi) {
    lo.x = dec1_e5m2(u & 0xFF); lo.y = dec1_e5m2((u >> 8) & 0xFF);
    hi.x = dec1_e5m2((u >> 16) & 0xFF); hi.y = dec1_e5m2(u >> 24);
}
#endif

// Per-edge lookup helper: concatenated index -> (global seg id, src)
__device__ __forceinline__ void edge_lookup(int i,
    const int* __restrict__ s0, const int* __restrict__ d0, int E0,
    const int* __restrict__ s1, const int* __restrict__ d1, int E1,
    const int* __restrict__ s2, const int* __restrict__ d2, int E2,
    const int* __restrict__ s3, const int* __restrict__ d3,
    int& g, int& sv)
{
    if (i < E0)                { g = BASE_GW + d0[i];                 sv = s0 ? s0[i] : 0; }
    else if (i < E0 + E1)      { int j = i - E0;           g = BASE_GP + d1[j]; sv = s1 ? s1[j] : 0; }
    else if (i < E0 + E1 + E2) { int j = i - E0 - E1;      g = BASE_SP + d2[j]; sv = s2 ? s2[j] : 0; }
    else                       { int j = i - E0 - E1 - E2; g = BASE_PS + d3[j]; sv = s3 ? s3[j] : 0; }
}

// ---------------------------------------------------------------------------
// Phase 1: cast features to packed bf16 rows + fp8 rows (xp|xg|xs) + per-block
// LDS histogram over 1250 coarse bins. 4-way sub-histograms quarter the
// same-address LDS-atomic contention. countMat[k][bin] = chunk k's bin count.
// ---------------------------------------------------------------------------
__global__ void __launch_bounds__(1024)
count_cast(const int* __restrict__ d0, int E0, const int* __restrict__ d1, int E1,
           const int* __restrict__ d2, int E2, const int* __restrict__ d3, int E3,
           const float* __restrict__ xp, const float* __restrict__ xg,
           const float* __restrict__ xs, unsigned short* __restrict__ x16,
           unsigned int* __restrict__ x8, int* __restrict__ countMat)
{
    const int T0 = 20000 * 16, T1 = 120000 * 16, TT = N_XROW * 16;  // float4 units
    for (int i = blockIdx.x * 1024 + threadIdx.x; i < TT; i += NB_FILL * 1024) {
        float4 v;
        if (i < T0)      v = ((const float4*)xp)[i];
        else if (i < T1) v = ((const float4*)xg)[i - T0];
        else             v = ((const float4*)xs)[i - T1];
        ushort4 o;
        o.x = f2bf(v.x); o.y = f2bf(v.y); o.z = f2bf(v.z); o.w = f2bf(v.w);
        ((ushort4*)x16)[i] = o;
        x8[i] = enc_fp8x4(v);
    }

    __shared__ int h[4][NBIN];          // 20 KB; 4-way to cut atomic contention
    for (int i = threadIdx.x; i < NBIN; i += 1024) {
        h[0][i] = 0; h[1][i] = 0; h[2][i] = 0; h[3][i] = 0;
    }
    __syncthreads();
    int sub = threadIdx.x & 3;
    int total = E0 + E1 + E2 + E3;
    int CH = (total + NB_FILL - 1) / NB_FILL;
    int s = blockIdx.x * CH;
    int e = s + CH; if (e > total) e = total;
    for (int i0 = s + threadIdx.x * 4; i0 < e; i0 += 1024 * 4) {
        int gs[4];
        int m = e - i0; if (m > 4) m = 4;
        #pragma unroll
        for (int u = 0; u < 4; u++) {
            if (u < m) {
                int g, sv;
                edge_lookup(i0 + u, nullptr, d0, E0, nullptr, d1, E1,
                            nullptr, d2, E2, nullptr, d3, g, sv);
                gs[u] = g;
            }
        }
        #pragma unroll
        for (int u = 0; u < 4; u++)
            if (u < m) atomicAdd(&h[sub][gs[u] >> 7], 1);
    }
    __syncthreads();
    for (int i = threadIdx.x; i < NBIN; i += 1024)
        countMat[blockIdx.x * NBIN + i] = h[0][i] + h[1][i] + h[2][i] + h[3][i];
}

// ---------------------------------------------------------------------------
// Phase 2 (scan FUSED in): per-chunk bin-sort in LDS, then ONE coalesced
// flush. Block k first scans its own countMat row into lofs (replaces the
// old scan_rows kernel). Global writes are 16 MB streaming (scattered
// cross-XCD writes showed ~16x amplification in R1/R6).
// eb layout: chunk-major; bin b's edges of chunk k at [k*CH + lofs[k][b]).
// Also zeroes the sort_agg work queues (block 0).
// ---------------------------------------------------------------------------
__global__ void __launch_bounds__(1024)
fill_stage(const int* __restrict__ s0, const int* __restrict__ d0, int E0,
           const int* __restrict__ s1, const int* __restrict__ d1, int E1,
           const int* __restrict__ s2, const int* __restrict__ d2, int E2,
           const int* __restrict__ s3, const int* __restrict__ d3, int E3,
           const int* __restrict__ countMat, int* __restrict__ lofs,
           int* __restrict__ eb, int* __restrict__ qcnt)
{
    __shared__ int cur[NBIN];          // 5 KB   — per-bin cursors (chunk-local)
    __shared__ int scanb[2048];        // 8 KB   — row scan workspace
    __shared__ int stage[STAGE_CAP];   // 32 KB  — chunk sorted by bin
    int k = blockIdx.x;
    int t = threadIdx.x;

    // Exclusive scan of countMat row k -> cur + lofs (was scan_rows).
    int v0 = (t < NBIN) ? countMat[k * NBIN + t] : 0;
    int v1 = (t + 1024 < NBIN) ? countMat[k * NBIN + t + 1024] : 0;
    scanb[t] = v0; scanb[t + 1024] = v1;
    __syncthreads();
    #pragma unroll
    for (int off = 1; off < 2048; off <<= 1) {
        int a = (t >= off) ? scanb[t - off] : 0;
        int b2 = (t + 1024 >= off) ? scanb[t + 1024 - off] : 0;
        __syncthreads();
        scanb[t] += a; scanb[t + 1024] += b2;
        __syncthreads();
    }
    if (t < NBIN)        { int ex = scanb[t] - v0;        cur[t] = ex;        lofs[k * NBIN + t] = ex; }
    if (t + 1024 < NBIN) { int ex = scanb[t + 1024] - v1; cur[t + 1024] = ex; lofs[k * NBIN + t + 1024] = ex; }
    if (k == 0 && t < 2) qcnt[t] = 0;
    __syncthreads();

    int total = E0 + E1 + E2 + E3;
    int CH = (total + NB_FILL - 1) / NB_FILL;
    int s = k * CH;
    int e = s + CH; if (e > total) e = total;
    for (int i0 = s + threadIdx.x * 4; i0 < e; i0 += 1024 * 4) {
        int g[4], sv[4];
        int m = e - i0; if (m > 4) m = 4;
        #pragma unroll
        for (int u = 0; u < 4; u++)
            if (u < m) edge_lookup(i0 + u, s0, d0, E0, s1, d1, E1,
                                   s2, d2, E2, s3, d3, g[u], sv[u]);
        #pragma unroll
        for (int u = 0; u < 4; u++) {
            if (u < m) {
                int slot = atomicAdd(&cur[g[u] >> 7], 1);
                stage[slot] = sv[u] | ((g[u] & 127) << 20);
            }
        }
    }
    __syncthreads();
    int n = e - s;
    for (int i = threadIdx.x; i < n; i += 1024) eb[s + i] = stage[i];
}

// ---------------------------------------------------------------------------
// Phase 2b: tiled transpose of countMat/lofs (512x1250 -> 1250x512) so
// sort_agg's per-bin metadata reads are CONTIGUOUS 2KB loads instead of
// 512 x 4B column-strided reads (64KB of lines per block for 4KB used).
// ---------------------------------------------------------------------------
__global__ void __launch_bounds__(1024)
transp(const int* __restrict__ cm, const int* __restrict__ lf,
       int* __restrict__ cmT, int* __restrict__ lfT)
{
    __shared__ int t0[32][33], t1[32][33];
    int tx = threadIdx.x & 31, ty = threadIdx.x >> 5;
    int c = blockIdx.x * 32 + tx;         // bin
    int r = blockIdx.y * 32 + ty;         // chunk (<512 always)
    if (c < NBIN) {
        t0[ty][tx] = cm[r * NBIN + c];
        t1[ty][tx] = lf[r * NBIN + c];
    }
    __syncthreads();
    int c2 = blockIdx.x * 32 + ty;        // bin (output row)
    int r2 = blockIdx.y * 32 + tx;        // chunk (output col)
    if (c2 < NBIN) {
        cmT[c2 * NB_FILL + r2] = t0[tx][ty];
        lfT[c2 * NB_FILL + r2] = t1[tx][ty];
    }
}

// ---------------------------------------------------------------------------
// Phase 3+4 FUSED: XCD-partitioned dynamic bin queues (leader reads XCC_ID,
// XCDs 0-2 prefer the 156 GP-heavy bins whose gathers hit xg (6.4MB), XCDs
// 3-7 take GW/SP/PS whose sources xp+xs (2.56MB) fit L2 entirely; atomic
// queues with cross-fallback are correct regardless of XCC_ID value).
// Then: compacted coalesced run assembly (binary search over cposS), pass 2
// LDS-only perm scatter, proven 2-nodes-per-wave fp8 agg.
// cm/lf accessed via runtime strides: transposed (sA=1,sB=512) when ws
// allows, else row-major (sA=NBIN,sB=1).
// ---------------------------------------------------------------------------
__global__ void __launch_bounds__(1024)
sort_agg(const int* __restrict__ cm, const int* __restrict__ lf,
         int sA, int sB, int* __restrict__ qcnt,
         const int* __restrict__ eb, const unsigned int* __restrict__ x8,
         unsigned short* __restrict__ meanAll, int E_total)
{
    __shared__ int stage[SORT_CAP];            // 48 KB — words in COMPACTED order
    __shared__ unsigned short perm[SORT_CAP];  // 24 KB — sorted pos -> compacted idx
    __shared__ int rs[NB_FILL];                // run start (global index) per chunk
    __shared__ int cposS[NB_FILL + 1];         // compacted prefix of run lengths
    __shared__ int cnt[128], basep[128], cur[128], lstart[128];
    __shared__ int sbin;
    int lane = threadIdx.x & 63;
    int t = threadIdx.x;
    int CH = (E_total + NB_FILL - 1) / NB_FILL;

    if (t == 0) {
        // HW_REG_XCC_ID = hwreg id 20 (CDNA3+); size 32, offset 0.
        unsigned xcc = (unsigned)__builtin_amdgcn_s_getreg((31 << 11) | 20) & 0xfu;
        int pref = (xcc < 3u) ? 0 : 1;
        int bsel = -1;
        int idx = atomicAdd(&qcnt[pref], 1);
        if (pref == 0) {
            if (idx < N_GPQ) bsel = 781 + idx;
            else {
                int j = atomicAdd(&qcnt[1], 1);
                if (j < N_OTQ) bsel = (j < 781) ? j : (937 + (j - 781));
            }
        } else {
            if (idx < N_OTQ) bsel = (idx < 781) ? idx : (937 + (idx - 781));
            else {
                int j = atomicAdd(&qcnt[0], 1);
                if (j < N_GPQ) bsel = 781 + j;
            }
        }
        sbin = bsel;
    }
    __syncthreads();
    int b = sbin;
    if (b < 0) return;

    if (t < 128) cnt[t] = 0;
    if (t < NB_FILL) {
        int ckv = cm[t * sA + b * sB];
        rs[t] = t * CH + lf[t * sA + b * sB];
        cposS[t + 1] = ckv;
    }
    if (t == 0) cposS[0] = 0;
    __syncthreads();
    // inclusive scan of cposS[1..512] (Hillis-Steele over 512)
    #pragma unroll
    for (int off = 1; off < NB_FILL; off <<= 1) {
        int v = 0;
        if (t < NB_FILL && t >= off) v = cposS[t + 1 - off];
        __syncthreads();
        if (t < NB_FILL) cposS[t + 1] += v;
        __syncthreads();
    }
    int n = cposS[NB_FILL];
    if (n > SORT_CAP) n = SORT_CAP;       // statistically unreachable (20 sigma)

    // Pass 1: compacted coalesced read; resolve rb; store word; count degrees.
    for (int i = t; i < n; i += 1024) {
        int lo = 0, hi = NB_FILL;
        #pragma unroll
        for (int it = 0; it < 9; it++) {   // 2^9 = 512
            int mid = (lo + hi) >> 1;
            if (cposS[mid] <= i) lo = mid; else hi = mid;
        }
        int w = eb[rs[lo] + i - cposS[lo]];
        int dl = w >> 20;
        int g = (b << 7) + dl;
        int rb = (g < BASE_GP) ? 0 : (g < BASE_SP) ? 20000
               : (g < BASE_PS) ? 120000 : 0;
        stage[i] = ((w & 0xFFFFF) + rb) | (dl << 20);   // row id (<2^20) | node
        atomicAdd(&cnt[dl], 1);
    }
    __syncthreads();
    if (t < 128) basep[t] = cnt[t];
    __syncthreads();
    #pragma unroll
    for (int off = 1; off < 128; off <<= 1) {
        int v = 0;
        if (t < 128 && t >= off) v = basep[t - off];
        __syncthreads();
        if (t < 128) basep[t] += v;
        __syncthreads();
    }
    if (t < 128) {
        int ex = basep[t] - cnt[t];       // exclusive
        cur[t] = ex;
        lstart[t] = ex;
    }
    __syncthreads();

    // Pass 2 (LDS-only): scatter compacted indices into sorted perm positions.
    for (int i = t; i < n; i += 1024) {
        int dl = stage[i] >> 20;
        int slot = atomicAdd(&cur[dl], 1);
        perm[slot] = (unsigned short)i;
    }
    __syncthreads();

    // Aggregate: 16 waves x 4 iterations x 2 nodes/wave = 128 nodes.
    int wv = threadIdx.x >> 6;        // 0..15
    int h  = lane >> 5;
    int eq = (lane >> 3) & 3;
    int fc = lane & 7;
    int l32 = lane & 31;
    for (int it = 0; it < 4; it++) {
        int nl = 2 * (it * 16 + wv) + h;      // local node 0..127 (per half)
        int s0 = lstart[nl];
        int c0 = cnt[nl];
        if (s0 + c0 > SORT_CAP) c0 = SORT_CAP - s0;   // unreachable guard
        f32x2 a01 = {0.f,0.f}, a23 = {0.f,0.f}, a45 = {0.f,0.f}, a67 = {0.f,0.f};
        int j = 0;
        for (; j + 32 <= c0; j += 32) {
            int ev = stage[perm[s0 + j + l32]] & 0xFFFFF;
            #pragma unroll
            for (int q = 0; q < 8; q++) {
                int id = __shfl(ev, h * 32 + 4 * q + eq);
                uint2 v = *(const uint2*)(x8 + (((size_t)id) << 4) + fc * 2);
                f32x2 lo0, hi0, lo1, hi1;
                dec_fp8x4v(v.x, lo0, hi0);
                dec_fp8x4v(v.y, lo1, hi1);
                a01 += lo0; a23 += hi0; a45 += lo1; a67 += hi1;
            }
        }
        if (j < c0) {
            int blk = c0 - j;
            int ev = (l32 < blk) ? (stage[perm[s0 + j + l32]] & 0xFFFFF) : 0;
            int ng = (blk + 3) >> 2;
            for (int q = 0; q < ng; q++) {
                int idx = 4 * q + eq;
                int id = __shfl(ev, h * 32 + idx);
                if (idx < blk) {
                    uint2 v = *(const uint2*)(x8 + (((size_t)id) << 4) + fc * 2);
                    f32x2 lo0, hi0, lo1, hi1;
                    dec_fp8x4v(v.x, lo0, hi0);
                    dec_fp8x4v(v.y, lo1, hi1);
                    a01 += lo0; a23 += hi0; a45 += lo1; a67 += hi1;
                }
            }
        }
        float f[8] = {a01.x, a01.y, a23.x, a23.y, a45.x, a45.y, a67.x, a67.y};
        #pragma unroll
        for (int r = 0; r < 8; r++) {
            f[r] += __shfl_xor(f[r], 8);
            f[r] += __shfl_xor(f[r], 16);
        }
        if (eq == 0) {
            float inv = 1.0f / (float)(c0 > 1 ? c0 : 1);
            ushort4 o0, o1;
            o0.x = f2bf(f[0] * inv); o0.y = f2bf(f[1] * inv);
            o0.z = f2bf(f[2] * inv); o0.w = f2bf(f[3] * inv);
            o1.x = f2bf(f[4] * inv); o1.y = f2bf(f[5] * inv);
            o1.z = f2bf(f[6] * inv); o1.w = f2bf(f[7] * inv);
            int gnode = (b << 7) + nl;
            ushort4* dst = (ushort4*)(meanAll + (size_t)gnode * 64 + fc * 8);
            dst[0] = o0;
            dst[1] = o1;
        }
    }
}

// ---------------------------------------------------------------------------
// Fused node-update kernel bodies. A-fragments loaded DIRECTLY from global;
// shared mem = W only; one barrier total.
// ---------------------------------------------------------------------------
__device__ __forceinline__ void
head_body(const unsigned short* __restrict__ x16r,
          const unsigned short* __restrict__ mean,
          const float* __restrict__ Wl, const float* __restrict__ Wr,
          const float* __restrict__ b, const float* __restrict__ Wlin,
          const float* __restrict__ b_lin, const float* __restrict__ alpha,
          float* __restrict__ out, int N, int bid, int nblocks,
          unsigned short* __restrict__ smem)
{
    unsigned short* sW = smem;            // [128][136]

    for (int i = threadIdx.x; i < 64 * 128; i += 256) {
        int k = i >> 7, col = i & 127;
        sW[col * 136 + k]      = f2bf(Wl[k * 128 + col]);
        sW[col * 136 + 64 + k] = f2bf(Wr[k * 128 + col]);
    }

    int lane = threadIdx.x & 63;
    int wid  = threadIdx.x >> 6;
    int c    = lane & 15;
    int quad = lane >> 4;
    float wl_c[8], b_c[8];
    #pragma unroll
    for (int t = 0; t < 8; t++) {
        wl_c[t] = Wlin[t * 16 + c];
        b_c[t]  = b[t * 16 + c];
    }
    float blin = b_lin[0], al = alpha[0];
    __syncthreads();   // sW ready; no further barriers

    int ntiles = (N + 63) >> 6;
    for (int tile = bid; tile < ntiles; tile += nblocks) {
        int base = tile << 6;
        int node = base + wid * 16 + c;       // A-row this lane reads
        bool valid = node < N;
        const unsigned short* mrow = mean + (size_t)node * 64;
        const unsigned short* xrow = x16r + (size_t)node * 64;

        f32x4 acc[8] = {};
        #pragma unroll
        for (int step = 0; step < 4; step++) {
            short8 a = {};
            if (valid) {
                const unsigned short* src = (step < 2)
                    ? (mrow + step * 32 + quad * 8)
                    : (xrow + (step - 2) * 32 + quad * 8);
                a = *(const short8*)src;
            }
            #pragma unroll
            for (int t = 0; t < 8; t++) {
                short8 bb = *(const short8*)&sW[(t * 16 + c) * 136 + step * 32 + quad * 8];
                acc[t] = __builtin_amdgcn_mfma_f32_16x16x32_bf16(a, bb, acc[t], 0, 0, 0);
            }
        }

        float p[4] = {0.f, 0.f, 0.f, 0.f};
        #pragma unroll
        for (int t = 0; t < 8; t++) {
            #pragma unroll
            for (int r = 0; r < 4; r++) {
                float h = fmaxf(acc[t][r] + b_c[t], 0.0f);
                p[r] += h * wl_c[t];
            }
        }
        #pragma unroll
        for (int m = 1; m < 16; m <<= 1) {
            #pragma unroll
            for (int r = 0; r < 4; r++) p[r] += __shfl_xor(p[r], m);
        }
        if (c == 0) {
            #pragma unroll
            for (int r = 0; r < 4; r++) {
                int onode = base + wid * 16 + quad * 4 + r;
                if (onode < N) {
                    float y = p[r] + blin;
                    out[onode] = y > 0.0f ? y : al * y;
                }
            }
        }
    }
}

__device__ __forceinline__ void
pfas_body(const unsigned short* __restrict__ x16p,
          const unsigned short* __restrict__ meanGP,
          const unsigned short* __restrict__ meanSP,
          const float* __restrict__ WlGP, const float* __restrict__ WrGP,
          const float* __restrict__ bGP,
          const float* __restrict__ WlSP, const float* __restrict__ WrSP,
          const float* __restrict__ bSP,
          float* __restrict__ out, int N, int bid, int nblocks,
          unsigned short* __restrict__ smem)
{
    unsigned short* sW = smem;            // [128][200]

    for (int i = threadIdx.x; i < 64 * 128; i += 256) {
        int k = i >> 7, col = i & 127;
        sW[col * 200 + k]       = f2bf(WlGP[k * 128 + col]);
        sW[col * 200 + 64 + k]  = f2bf(WlSP[k * 128 + col]);
        sW[col * 200 + 128 + k] = f2bf(WrGP[k * 128 + col] + WrSP[k * 128 + col]);
    }

    int lane = threadIdx.x & 63;
    int wid  = threadIdx.x >> 6;
    int c    = lane & 15;
    int quad = lane >> 4;
    int rg   = (wid & 1) * 16;
    int cg   = (wid >> 1) * 4;
    float b_c[4];
    #pragma unroll
    for (int t = 0; t < 4; t++)
        b_c[t] = bGP[(cg + t) * 16 + c] + bSP[(cg + t) * 16 + c];
    __syncthreads();   // sW ready; no further barriers

    int ntiles = (N + 31) >> 5;
    for (int tile = bid; tile < ntiles; tile += nblocks) {
        int base = tile << 5;
        int node = base + rg + c;             // A-row this lane reads
        bool valid = node < N;
        const unsigned short* grow = meanGP + (size_t)node * 64;
        const unsigned short* srow = meanSP + (size_t)node * 64;
        const unsigned short* xrow = x16p + (size_t)node * 64;

        f32x4 acc[4] = {};
        #pragma unroll
        for (int step = 0; step < 6; step++) {
            short8 a = {};
            if (valid) {
                const unsigned short* src = (step < 2)
                    ? (grow + step * 32 + quad * 8)
                    : (step < 4) ? (srow + (step - 2) * 32 + quad * 8)
                                 : (xrow + (step - 4) * 32 + quad * 8);
                a = *(const short8*)src;
            }
            #pragma unroll
            for (int t = 0; t < 4; t++) {
                short8 bb = *(const short8*)&sW[((cg + t) * 16 + c) * 200 + step * 32 + quad * 8];
                acc[t] = __builtin_amdgcn_mfma_f32_16x16x32_bf16(a, bb, acc[t], 0, 0, 0);
            }
        }

        #pragma unroll
        for (int t = 0; t < 4; t++) {
            int col = (cg + t) * 16 + c;
            #pragma unroll
            for (int r = 0; r < 4; r++) {
                int onode = base + rg + quad * 4 + r;
                if (onode < N) {
                    float h = fmaxf(acc[t][r] + b_c[t], 0.0f);
                    out[(size_t)onode * 128 + col] = h;
                }
            }
        }
    }
}

// Fused node-update kernel: blocks [0,512) GW head, [512,672) SW head,
// [672,896) PFAS.  LDS = 51200 B -> 3 blocks/CU.
__global__ void __launch_bounds__(256)
node_mfma(const unsigned short* __restrict__ x16,
          const unsigned short* __restrict__ meanAll,
          const float* __restrict__ Wl_pg, const float* __restrict__ Wr_pg,
          const float* __restrict__ b_pg,
          const float* __restrict__ Wl_ps, const float* __restrict__ Wr_ps,
          const float* __restrict__ b_ps,
          const float* __restrict__ Wl_gp, const float* __restrict__ Wr_gp,
          const float* __restrict__ b_gp,
          const float* __restrict__ Wl_sp, const float* __restrict__ Wr_sp,
          const float* __restrict__ b_sp,
          const float* __restrict__ W_lin, const float* __restrict__ b_lin,
          const float* __restrict__ alpha,
          float* __restrict__ out_gw, float* __restrict__ out_sw,
          float* __restrict__ out_pfas)
{
    __shared__ __align__(16) unsigned short smem[25600];   // 51200 B union
    int bx = blockIdx.x;
    if (bx < 512) {
        head_body(x16 + (size_t)20000 * 64, meanAll + (size_t)BASE_GW * 64,
                  Wl_pg, Wr_pg, b_pg, W_lin, b_lin, alpha,
                  out_gw, N_GW, bx, 512, smem);
    } else if (bx < 672) {
        head_body(x16 + (size_t)120000 * 64, meanAll + (size_t)BASE_PS * 64,
                  Wl_ps, Wr_ps, b_ps, W_lin, b_lin, alpha,
                  out_sw, N_SW, bx - 512, 160, smem);
    } else {
        pfas_body(x16, meanAll + (size_t)BASE_GP * 64, meanAll + (size_t)BASE_SP * 64,
                  Wl_gp, Wr_gp, b_gp, Wl_sp, Wr_sp, b_sp,
                  out_pfas, N_PFAS, bx - 672, 224, smem);
    }
}

extern "C" void kernel_launch(void* const* d_in, const int* in_sizes, int n_in,
                              void* d_out, int out_size, void* d_ws, size_t ws_size,
                              hipStream_t stream)
{
    const float* x_pfas = (const float*)d_in[0];
    const float* x_gw   = (const float*)d_in[1];
    const float* x_sw   = (const float*)d_in[2];
    const int* pg_src = (const int*)d_in[3];
    const int* pg_dst = (const int*)d_in[4];
    const int* gp_src = (const int*)d_in[5];
    const int* gp_dst = (const int*)d_in[6];
    const int* sp_src = (const int*)d_in[7];
    const int* sp_dst = (const int*)d_in[8];
    const int* ps_src = (const int*)d_in[9];
    const int* ps_dst = (const int*)d_in[10];
    const float* Wl_pg = (const float*)d_in[11];
    const float* Wr_pg = (const float*)d_in[12];
    const float* b_pg  = (const float*)d_in[13];
    const float* Wl_gp = (const float*)d_in[14];
    const float* Wr_gp = (const float*)d_in[15];
    const float* b_gp  = (const float*)d_in[16];
    const float* Wl_sp = (const float*)d_in[17];
    const float* Wr_sp = (const float*)d_in[18];
    const float* b_sp  = (const float*)d_in[19];
    const float* Wl_ps = (const float*)d_in[20];
    const float* Wr_ps = (const float*)d_in[21];
    const float* b_ps  = (const float*)d_in[22];
    const float* W_lin = (const float*)d_in[23];
    const float* b_lin = (const float*)d_in[24];
    const float* alpha = (const float*)d_in[25];

    float* out = (float*)d_out;
    float* out_pfas = out;                                 // 20000*128
    float* out_gw   = out + (size_t)N_PFAS * 128;          // 100000
    float* out_sw   = out_gw + N_GW;                       // 20000

    int E_PG = in_sizes[3];
    int E_GP = in_sizes[5];
    int E_SP = in_sizes[7];
    int E_PS = in_sizes[9];
    int E_total = E_PG + E_GP + E_SP + E_PS;               // 4,000,000

    // Workspace layout (~73.7 MB with transposed metadata; guarded):
    unsigned short* meanAll = (unsigned short*)d_ws;       // 160000*64 bf16 = 20.48 MB
    int* countMat  = (int*)(meanAll + (size_t)N_SEG * 64); // 512*1250 ints = 2.56 MB
    int* lofs      = countMat + NB_FILL * NBIN;            // 512*1250 ints = 2.56 MB
    int* qcnt      = lofs + NB_FILL * NBIN;                // 8 ints (2 used)
    int* edge_binned = qcnt + 8;                           // 4,000,000 ints (16 MB)
    unsigned short* x16 = (unsigned short*)(edge_binned + E_total);  // 17.92 MB
    unsigned int* x8 = (unsigned int*)(x16 + (size_t)N_XROW * 64);   // 8.96 MB
    int* cmT = (int*)(x8 + (size_t)N_XROW * 16);           // 2.56 MB (bin-major)
    int* lfT = cmT + NB_FILL * NBIN;                       // 2.56 MB (bin-major)
    size_t needT = (size_t)((char*)(lfT + NB_FILL * NBIN) - (char*)d_ws);
    bool useT = (ws_size >= needT);

    count_cast<<<NB_FILL, 1024, 0, stream>>>(pg_dst, E_PG, gp_dst, E_GP,
                                             sp_dst, E_SP, ps_dst, E_PS,
                                             x_pfas, x_gw, x_sw, x16, x8,
                                             countMat);

    fill_stage<<<NB_FILL, 1024, 0, stream>>>(pg_src, pg_dst, E_PG,
                                             gp_src, gp_dst, E_GP,
                                             sp_src, sp_dst, E_SP,
                                             ps_src, ps_dst, E_PS,
                                             countMat, lofs, edge_binned, qcnt);

    if (useT) {
        transp<<<dim3(40, 16), 1024, 0, stream>>>(countMat, lofs, cmT, lfT);
        sort_agg<<<NBIN, 1024, 0, stream>>>(cmT, lfT, 1, NB_FILL, qcnt,
                                            edge_binned, x8, meanAll, E_total);
    } else {
        sort_agg<<<NBIN, 1024, 0, stream>>>(countMat, lofs, NBIN, 1, qcnt,
                                            edge_binned, x8, meanAll, E_total);
    }

    node_mfma<<<896, 256, 0, stream>>>(x16, meanAll,
                                       Wl_pg, Wr_pg, b_pg,
                                       Wl_ps, Wr_ps, b_ps,
                                       Wl_gp, Wr_gp, b_gp,
                                       Wl_sp, Wr_sp, b_sp,
                                       W_lin, b_lin, alpha,
                                       out_gw, out_sw, out_pfas);
}

// Round 10
// 266.749 us; speedup vs baseline: 1.1143x; 1.1143x over previous
//
#include <hip/hip_runtime.h>
#include <hip/hip_bf16.h>

// Problem constants (from reference)
#define N_PFAS 20000
#define N_GW   100000
#define N_SW   20000
#define N_SEG  160000          // GW[0,100k) GP[100k,120k) SP[120k,140k) PS[140k,160k)
#define BASE_GW 0
#define BASE_GP 100000
#define BASE_SP 120000
#define BASE_PS 140000
#define NBIN 1250              // 160000 / 128 exactly (bin = 128 dst nodes)
#define NB_FILL 512            // chunk count (count/fill blocks)
#define SORT_CAP 12288         // LDS staging (max real bin ~10.3k; 48KB)
#define STAGE_CAP 8192         // fill_stage per-chunk LDS (CH = 7813)
#define N_XROW 140000          // xp 20000 | xg 100000 | xs 20000 packed rows

typedef __attribute__((ext_vector_type(8))) short short8;   // 8 bf16 (4 VGPRs)
typedef __attribute__((ext_vector_type(4))) float f32x4;    // MFMA C/D frag
typedef __attribute__((ext_vector_type(2))) float f32x2;

__device__ __forceinline__ unsigned short f2bf(float f) {
    union { float f; unsigned int u; } v;
    v.f = f;
    unsigned int u = v.u;
    unsigned int r = (u + 0x7fffu + ((u >> 16) & 1u)) >> 16;  // RNE
    return (unsigned short)r;
}

// ---- fp8 encode/decode: HW e4m3 converters if available, else e5m2 ----
#if __has_builtin(__builtin_amdgcn_cvt_pk_f32_fp8) && __has_builtin(__builtin_amdgcn_cvt_pk_fp8_f32)
#define FP8_HW 1
__device__ __forceinline__ unsigned int enc_fp8x4(float4 v) {
    int r = __builtin_amdgcn_cvt_pk_fp8_f32(v.x, v.y, 0, false);
    r = __builtin_amdgcn_cvt_pk_fp8_f32(v.z, v.w, r, true);
    return (unsigned int)r;
}
__device__ __forceinline__ void dec_fp8x4v(unsigned int u, f32x2& lo, f32x2& hi) {
    lo = __builtin_amdgcn_cvt_pk_f32_fp8(u, false);
    hi = __builtin_amdgcn_cvt_pk_f32_fp8(u, true);
}
#else
// e5m2 = top byte of IEEE f16. Encode: f32->f16 (RNE) then RNE-round top byte.
__device__ __forceinline__ unsigned char enc1_e5m2(float f) {
    union { unsigned short u; _Float16 h; } cv;
    cv.h = (_Float16)f;
    unsigned int u = cv.u;
    unsigned int r = (u + 0x7Fu + ((u >> 8) & 1u)) >> 8;
    return (unsigned char)(r > 255u ? 255u : r);
}
__device__ __forceinline__ unsigned int enc_fp8x4(float4 v) {
    return (unsigned int)enc1_e5m2(v.x) | ((unsigned int)enc1_e5m2(v.y) << 8)
         | ((unsigned int)enc1_e5m2(v.z) << 16) | ((unsigned int)enc1_e5m2(v.w) << 24);
}
__device__ __forceinline__ float dec1_e5m2(unsigned int b) {
    union { unsigned short u; _Float16 h; } cv;
    cv.u = (unsigned short)(b << 8);
    return (float)cv.h;
}
__device__ __forceinline__ void dec_fp8x4v(unsigned int u, f32x2& lo, f32x2& hi) {
    lo.x = dec1_e5m2(u & 0xFF); lo.y = dec1_e5m2((u >> 8) & 0xFF);
    hi.x = dec1_e5m2((u >> 16) & 0xFF); hi.y = dec1_e5m2(u >> 24);
}
#endif

// Per-edge lookup helper: concatenated index -> (global seg id, src)
__device__ __forceinline__ void edge_lookup(int i,
    const int* __restrict__ s0, const int* __restrict__ d0, int E0,
    const int* __restrict__ s1, const int* __restrict__ d1, int E1,
    const int* __restrict__ s2, const int* __restrict__ d2, int E2,
    const int* __restrict__ s3, const int* __restrict__ d3,
    int& g, int& sv)
{
    if (i < E0)                { g = BASE_GW + d0[i];                 sv = s0 ? s0[i] : 0; }
    else if (i < E0 + E1)      { int j = i - E0;           g = BASE_GP + d1[j]; sv = s1 ? s1[j] : 0; }
    else if (i < E0 + E1 + E2) { int j = i - E0 - E1;      g = BASE_SP + d2[j]; sv = s2 ? s2[j] : 0; }
    else                       { int j = i - E0 - E1 - E2; g = BASE_PS + d3[j]; sv = s3 ? s3[j] : 0; }
}

// ---------------------------------------------------------------------------
// Phase 1: cast features to packed bf16 rows + fp8 rows (xp|xg|xs) + per-block
// LDS histogram over 1250 coarse bins. 4-way sub-histograms quarter the
// same-address LDS-atomic contention. countMat[k][bin] = chunk k's bin count.
// ---------------------------------------------------------------------------
__global__ void __launch_bounds__(1024)
count_cast(const int* __restrict__ d0, int E0, const int* __restrict__ d1, int E1,
           const int* __restrict__ d2, int E2, const int* __restrict__ d3, int E3,
           const float* __restrict__ xp, const float* __restrict__ xg,
           const float* __restrict__ xs, unsigned short* __restrict__ x16,
           unsigned int* __restrict__ x8, int* __restrict__ countMat)
{
    const int T0 = 20000 * 16, T1 = 120000 * 16, TT = N_XROW * 16;  // float4 units
    for (int i = blockIdx.x * 1024 + threadIdx.x; i < TT; i += NB_FILL * 1024) {
        float4 v;
        if (i < T0)      v = ((const float4*)xp)[i];
        else if (i < T1) v = ((const float4*)xg)[i - T0];
        else             v = ((const float4*)xs)[i - T1];
        ushort4 o;
        o.x = f2bf(v.x); o.y = f2bf(v.y); o.z = f2bf(v.z); o.w = f2bf(v.w);
        ((ushort4*)x16)[i] = o;
        x8[i] = enc_fp8x4(v);
    }

    __shared__ int h[4][NBIN];          // 20 KB; 4-way to cut atomic contention
    for (int i = threadIdx.x; i < NBIN; i += 1024) {
        h[0][i] = 0; h[1][i] = 0; h[2][i] = 0; h[3][i] = 0;
    }
    __syncthreads();
    int sub = threadIdx.x & 3;
    int total = E0 + E1 + E2 + E3;
    int CH = (total + NB_FILL - 1) / NB_FILL;
    int s = blockIdx.x * CH;
    int e = s + CH; if (e > total) e = total;
    for (int i0 = s + threadIdx.x * 4; i0 < e; i0 += 1024 * 4) {
        int gs[4];
        int m = e - i0; if (m > 4) m = 4;
        #pragma unroll
        for (int u = 0; u < 4; u++) {
            if (u < m) {
                int g, sv;
                edge_lookup(i0 + u, nullptr, d0, E0, nullptr, d1, E1,
                            nullptr, d2, E2, nullptr, d3, g, sv);
                gs[u] = g;
            }
        }
        #pragma unroll
        for (int u = 0; u < 4; u++)
            if (u < m) atomicAdd(&h[sub][gs[u] >> 7], 1);
    }
    __syncthreads();
    for (int i = threadIdx.x; i < NBIN; i += 1024)
        countMat[blockIdx.x * NBIN + i] = h[0][i] + h[1][i] + h[2][i] + h[3][i];
}

// ---------------------------------------------------------------------------
// Phase 2 (scan FUSED in): per-chunk bin-sort in LDS, then ONE coalesced
// flush. Block k first scans its own countMat row into lofs (replaces the
// old scan_rows kernel). Global writes are 16 MB streaming (scattered
// cross-XCD writes showed ~16x amplification in R1/R6).
// eb layout: chunk-major; bin b's edges of chunk k at [k*CH + lofs[k][b]).
// ---------------------------------------------------------------------------
__global__ void __launch_bounds__(1024)
fill_stage(const int* __restrict__ s0, const int* __restrict__ d0, int E0,
           const int* __restrict__ s1, const int* __restrict__ d1, int E1,
           const int* __restrict__ s2, const int* __restrict__ d2, int E2,
           const int* __restrict__ s3, const int* __restrict__ d3, int E3,
           const int* __restrict__ countMat, int* __restrict__ lofs,
           int* __restrict__ eb)
{
    __shared__ int cur[NBIN];          // 5 KB   — per-bin cursors (chunk-local)
    __shared__ int scanb[2048];        // 8 KB   — row scan workspace
    __shared__ int stage[STAGE_CAP];   // 32 KB  — chunk sorted by bin
    int k = blockIdx.x;
    int t = threadIdx.x;

    // Exclusive scan of countMat row k -> cur + lofs (was scan_rows).
    int v0 = (t < NBIN) ? countMat[k * NBIN + t] : 0;
    int v1 = (t + 1024 < NBIN) ? countMat[k * NBIN + t + 1024] : 0;
    scanb[t] = v0; scanb[t + 1024] = v1;
    __syncthreads();
    #pragma unroll
    for (int off = 1; off < 2048; off <<= 1) {
        int a = (t >= off) ? scanb[t - off] : 0;
        int b2 = (t + 1024 >= off) ? scanb[t + 1024 - off] : 0;
        __syncthreads();
        scanb[t] += a; scanb[t + 1024] += b2;
        __syncthreads();
    }
    if (t < NBIN)        { int ex = scanb[t] - v0;        cur[t] = ex;        lofs[k * NBIN + t] = ex; }
    if (t + 1024 < NBIN) { int ex = scanb[t + 1024] - v1; cur[t + 1024] = ex; lofs[k * NBIN + t + 1024] = ex; }
    __syncthreads();

    int total = E0 + E1 + E2 + E3;
    int CH = (total + NB_FILL - 1) / NB_FILL;
    int s = k * CH;
    int e = s + CH; if (e > total) e = total;
    for (int i0 = s + threadIdx.x * 4; i0 < e; i0 += 1024 * 4) {
        int g[4], sv[4];
        int m = e - i0; if (m > 4) m = 4;
        #pragma unroll
        for (int u = 0; u < 4; u++)
            if (u < m) edge_lookup(i0 + u, s0, d0, E0, s1, d1, E1,
                                   s2, d2, E2, s3, d3, g[u], sv[u]);
        #pragma unroll
        for (int u = 0; u < 4; u++) {
            if (u < m) {
                int slot = atomicAdd(&cur[g[u] >> 7], 1);
                stage[slot] = sv[u] | ((g[u] & 127) << 20);
            }
        }
    }
    __syncthreads();
    int n = e - s;
    for (int i = threadIdx.x; i < n; i += 1024) eb[s + i] = stage[i];
}

// ---------------------------------------------------------------------------
// Phase 2b: tiled transpose of countMat/lofs (512x1250 -> 1250x512) so
// sort_agg's per-bin metadata reads are CONTIGUOUS 2KB loads instead of
// 512 x 4B column-strided reads (validated R8: FETCH 134 -> 92 MB).
// ---------------------------------------------------------------------------
__global__ void __launch_bounds__(1024)
transp(const int* __restrict__ cm, const int* __restrict__ lf,
       int* __restrict__ cmT, int* __restrict__ lfT)
{
    __shared__ int t0[32][33], t1[32][33];
    int tx = threadIdx.x & 31, ty = threadIdx.x >> 5;
    int c = blockIdx.x * 32 + tx;         // bin
    int r = blockIdx.y * 32 + ty;         // chunk (<512 always)
    if (c < NBIN) {
        t0[ty][tx] = cm[r * NBIN + c];
        t1[ty][tx] = lf[r * NBIN + c];
    }
    __syncthreads();
    int c2 = blockIdx.x * 32 + ty;        // bin (output row)
    int r2 = blockIdx.y * 32 + tx;        // chunk (output col)
    if (c2 < NBIN) {
        cmT[c2 * NB_FILL + r2] = t0[tx][ty];
        lfT[c2 * NB_FILL + r2] = t1[tx][ty];
    }
}

// ---------------------------------------------------------------------------
// Phase 3+4 FUSED: STATIC bin assignment b=(blockIdx+781)%NBIN (GP-heavy
// bins first, spread across ALL XCDs — R8 proved XCD-partitioned queues
// destroy load balance & request concurrency: 79->107us). Compacted
// coalesced run assembly (binary search over cposS), pass 2 LDS-only perm
// scatter, proven 2-nodes-per-wave fp8 agg.
// cm/lf accessed via runtime strides: transposed (sA=1,sB=512) when ws
// allows, else row-major (sA=NBIN,sB=1).
// ---------------------------------------------------------------------------
__global__ void __launch_bounds__(1024)
sort_agg(const int* __restrict__ cm, const int* __restrict__ lf,
         int sA, int sB,
         const int* __restrict__ eb, const unsigned int* __restrict__ x8,
         unsigned short* __restrict__ meanAll, int E_total)
{
    __shared__ int stage[SORT_CAP];            // 48 KB — words in COMPACTED order
    __shared__ unsigned short perm[SORT_CAP];  // 24 KB — sorted pos -> compacted idx
    __shared__ int rs[NB_FILL];                // run start (global index) per chunk
    __shared__ int cposS[NB_FILL + 1];         // compacted prefix of run lengths
    __shared__ int cnt[128], basep[128], cur[128], lstart[128];
    int lane = threadIdx.x & 63;
    int t = threadIdx.x;
    int b = (int)((blockIdx.x + 781u) % NBIN);   // GP-heavy bins first
    int CH = (E_total + NB_FILL - 1) / NB_FILL;

    if (t < 128) cnt[t] = 0;
    if (t < NB_FILL) {
        int ckv = cm[t * sA + b * sB];
        rs[t] = t * CH + lf[t * sA + b * sB];
        cposS[t + 1] = ckv;
    }
    if (t == 0) cposS[0] = 0;
    __syncthreads();
    // inclusive scan of cposS[1..512] (Hillis-Steele over 512)
    #pragma unroll
    for (int off = 1; off < NB_FILL; off <<= 1) {
        int v = 0;
        if (t < NB_FILL && t >= off) v = cposS[t + 1 - off];
        __syncthreads();
        if (t < NB_FILL) cposS[t + 1] += v;
        __syncthreads();
    }
    int n = cposS[NB_FILL];
    if (n > SORT_CAP) n = SORT_CAP;       // statistically unreachable (20 sigma)

    // Pass 1: compacted coalesced read; resolve rb; store word; count degrees.
    for (int i = t; i < n; i += 1024) {
        int lo = 0, hi = NB_FILL;
        #pragma unroll
        for (int it = 0; it < 9; it++) {   // 2^9 = 512
            int mid = (lo + hi) >> 1;
            if (cposS[mid] <= i) lo = mid; else hi = mid;
        }
        int w = eb[rs[lo] + i - cposS[lo]];
        int dl = w >> 20;
        int g = (b << 7) + dl;
        int rb = (g < BASE_GP) ? 0 : (g < BASE_SP) ? 20000
               : (g < BASE_PS) ? 120000 : 0;
        stage[i] = ((w & 0xFFFFF) + rb) | (dl << 20);   // row id (<2^20) | node
        atomicAdd(&cnt[dl], 1);
    }
    __syncthreads();
    if (t < 128) basep[t] = cnt[t];
    __syncthreads();
    #pragma unroll
    for (int off = 1; off < 128; off <<= 1) {
        int v = 0;
        if (t < 128 && t >= off) v = basep[t - off];
        __syncthreads();
        if (t < 128) basep[t] += v;
        __syncthreads();
    }
    if (t < 128) {
        int ex = basep[t] - cnt[t];       // exclusive
        cur[t] = ex;
        lstart[t] = ex;
    }
    __syncthreads();

    // Pass 2 (LDS-only): scatter compacted indices into sorted perm positions.
    for (int i = t; i < n; i += 1024) {
        int dl = stage[i] >> 20;
        int slot = atomicAdd(&cur[dl], 1);
        perm[slot] = (unsigned short)i;
    }
    __syncthreads();

    // Aggregate: 16 waves x 4 iterations x 2 nodes/wave = 128 nodes.
    int wv = threadIdx.x >> 6;        // 0..15
    int h  = lane >> 5;
    int eq = (lane >> 3) & 3;
    int fc = lane & 7;
    int l32 = lane & 31;
    for (int it = 0; it < 4; it++) {
        int nl = 2 * (it * 16 + wv) + h;      // local node 0..127 (per half)
        int s0 = lstart[nl];
        int c0 = cnt[nl];
        if (s0 + c0 > SORT_CAP) c0 = SORT_CAP - s0;   // unreachable guard
        f32x2 a01 = {0.f,0.f}, a23 = {0.f,0.f}, a45 = {0.f,0.f}, a67 = {0.f,0.f};
        int j = 0;
        for (; j + 32 <= c0; j += 32) {
            int ev = stage[perm[s0 + j + l32]] & 0xFFFFF;
            #pragma unroll
            for (int q = 0; q < 8; q++) {
                int id = __shfl(ev, h * 32 + 4 * q + eq);
                uint2 v = *(const uint2*)(x8 + (((size_t)id) << 4) + fc * 2);
                f32x2 lo0, hi0, lo1, hi1;
                dec_fp8x4v(v.x, lo0, hi0);
                dec_fp8x4v(v.y, lo1, hi1);
                a01 += lo0; a23 += hi0; a45 += lo1; a67 += hi1;
            }
        }
        if (j < c0) {
            int blk = c0 - j;
            int ev = (l32 < blk) ? (stage[perm[s0 + j + l32]] & 0xFFFFF) : 0;
            int ng = (blk + 3) >> 2;
            for (int q = 0; q < ng; q++) {
                int idx = 4 * q + eq;
                int id = __shfl(ev, h * 32 + idx);
                if (idx < blk) {
                    uint2 v = *(const uint2*)(x8 + (((size_t)id) << 4) + fc * 2);
                    f32x2 lo0, hi0, lo1, hi1;
                    dec_fp8x4v(v.x, lo0, hi0);
                    dec_fp8x4v(v.y, lo1, hi1);
                    a01 += lo0; a23 += hi0; a45 += lo1; a67 += hi1;
                }
            }
        }
        float f[8] = {a01.x, a01.y, a23.x, a23.y, a45.x, a45.y, a67.x, a67.y};
        #pragma unroll
        for (int r = 0; r < 8; r++) {
            f[r] += __shfl_xor(f[r], 8);
            f[r] += __shfl_xor(f[r], 16);
        }
        if (eq == 0) {
            float inv = 1.0f / (float)(c0 > 1 ? c0 : 1);
            ushort4 o0, o1;
            o0.x = f2bf(f[0] * inv); o0.y = f2bf(f[1] * inv);
            o0.z = f2bf(f[2] * inv); o0.w = f2bf(f[3] * inv);
            o1.x = f2bf(f[4] * inv); o1.y = f2bf(f[5] * inv);
            o1.z = f2bf(f[6] * inv); o1.w = f2bf(f[7] * inv);
            int gnode = (b << 7) + nl;
            ushort4* dst = (ushort4*)(meanAll + (size_t)gnode * 64 + fc * 8);
            dst[0] = o0;
            dst[1] = o1;
        }
    }
}

// ---------------------------------------------------------------------------
// Fused node-update kernel bodies. A-fragments loaded DIRECTLY from global;
// shared mem = W only; one barrier total.
// ---------------------------------------------------------------------------
__device__ __forceinline__ void
head_body(const unsigned short* __restrict__ x16r,
          const unsigned short* __restrict__ mean,
          const float* __restrict__ Wl, const float* __restrict__ Wr,
          const float* __restrict__ b, const float* __restrict__ Wlin,
          const float* __restrict__ b_lin, const float* __restrict__ alpha,
          float* __restrict__ out, int N, int bid, int nblocks,
          unsigned short* __restrict__ smem)
{
    unsigned short* sW = smem;            // [128][136]

    for (int i = threadIdx.x; i < 64 * 128; i += 256) {
        int k = i >> 7, col = i & 127;
        sW[col * 136 + k]      = f2bf(Wl[k * 128 + col]);
        sW[col * 136 + 64 + k] = f2bf(Wr[k * 128 + col]);
    }

    int lane = threadIdx.x & 63;
    int wid  = threadIdx.x >> 6;
    int c    = lane & 15;
    int quad = lane >> 4;
    float wl_c[8], b_c[8];
    #pragma unroll
    for (int t = 0; t < 8; t++) {
        wl_c[t] = Wlin[t * 16 + c];
        b_c[t]  = b[t * 16 + c];
    }
    float blin = b_lin[0], al = alpha[0];
    __syncthreads();   // sW ready; no further barriers

    int ntiles = (N + 63) >> 6;
    for (int tile = bid; tile < ntiles; tile += nblocks) {
        int base = tile << 6;
        int node = base + wid * 16 + c;       // A-row this lane reads
        bool valid = node < N;
        const unsigned short* mrow = mean + (size_t)node * 64;
        const unsigned short* xrow = x16r + (size_t)node * 64;

        f32x4 acc[8] = {};
        #pragma unroll
        for (int step = 0; step < 4; step++) {
            short8 a = {};
            if (valid) {
                const unsigned short* src = (step < 2)
                    ? (mrow + step * 32 + quad * 8)
                    : (xrow + (step - 2) * 32 + quad * 8);
                a = *(const short8*)src;
            }
            #pragma unroll
            for (int t = 0; t < 8; t++) {
                short8 bb = *(const short8*)&sW[(t * 16 + c) * 136 + step * 32 + quad * 8];
                acc[t] = __builtin_amdgcn_mfma_f32_16x16x32_bf16(a, bb, acc[t], 0, 0, 0);
            }
        }

        float p[4] = {0.f, 0.f, 0.f, 0.f};
        #pragma unroll
        for (int t = 0; t < 8; t++) {
            #pragma unroll
            for (int r = 0; r < 4; r++) {
                float h = fmaxf(acc[t][r] + b_c[t], 0.0f);
                p[r] += h * wl_c[t];
            }
        }
        #pragma unroll
        for (int m = 1; m < 16; m <<= 1) {
            #pragma unroll
            for (int r = 0; r < 4; r++) p[r] += __shfl_xor(p[r], m);
        }
        if (c == 0) {
            #pragma unroll
            for (int r = 0; r < 4; r++) {
                int onode = base + wid * 16 + quad * 4 + r;
                if (onode < N) {
                    float y = p[r] + blin;
                    out[onode] = y > 0.0f ? y : al * y;
                }
            }
        }
    }
}

__device__ __forceinline__ void
pfas_body(const unsigned short* __restrict__ x16p,
          const unsigned short* __restrict__ meanGP,
          const unsigned short* __restrict__ meanSP,
          const float* __restrict__ WlGP, const float* __restrict__ WrGP,
          const float* __restrict__ bGP,
          const float* __restrict__ WlSP, const float* __restrict__ WrSP,
          const float* __restrict__ bSP,
          float* __restrict__ out, int N, int bid, int nblocks,
          unsigned short* __restrict__ smem)
{
    unsigned short* sW = smem;            // [128][200]

    for (int i = threadIdx.x; i < 64 * 128; i += 256) {
        int k = i >> 7, col = i & 127;
        sW[col * 200 + k]       = f2bf(WlGP[k * 128 + col]);
        sW[col * 200 + 64 + k]  = f2bf(WlSP[k * 128 + col]);
        sW[col * 200 + 128 + k] = f2bf(WrGP[k * 128 + col] + WrSP[k * 128 + col]);
    }

    int lane = threadIdx.x & 63;
    int wid  = threadIdx.x >> 6;
    int c    = lane & 15;
    int quad = lane >> 4;
    int rg   = (wid & 1) * 16;
    int cg   = (wid >> 1) * 4;
    float b_c[4];
    #pragma unroll
    for (int t = 0; t < 4; t++)
        b_c[t] = bGP[(cg + t) * 16 + c] + bSP[(cg + t) * 16 + c];
    __syncthreads();   // sW ready; no further barriers

    int ntiles = (N + 31) >> 5;
    for (int tile = bid; tile < ntiles; tile += nblocks) {
        int base = tile << 5;
        int node = base + rg + c;             // A-row this lane reads
        bool valid = node < N;
        const unsigned short* grow = meanGP + (size_t)node * 64;
        const unsigned short* srow = meanSP + (size_t)node * 64;
        const unsigned short* xrow = x16p + (size_t)node * 64;

        f32x4 acc[4] = {};
        #pragma unroll
        for (int step = 0; step < 6; step++) {
            short8 a = {};
            if (valid) {
                const unsigned short* src = (step < 2)
                    ? (grow + step * 32 + quad * 8)
                    : (step < 4) ? (srow + (step - 2) * 32 + quad * 8)
                                 : (xrow + (step - 4) * 32 + quad * 8);
                a = *(const short8*)src;
            }
            #pragma unroll
            for (int t = 0; t < 4; t++) {
                short8 bb = *(const short8*)&sW[((cg + t) * 16 + c) * 200 + step * 32 + quad * 8];
                acc[t] = __builtin_amdgcn_mfma_f32_16x16x32_bf16(a, bb, acc[t], 0, 0, 0);
            }
        }

        #pragma unroll
        for (int t = 0; t < 4; t++) {
            int col = (cg + t) * 16 + c;
            #pragma unroll
            for (int r = 0; r < 4; r++) {
                int onode = base + rg + quad * 4 + r;
                if (onode < N) {
                    float h = fmaxf(acc[t][r] + b_c[t], 0.0f);
                    out[(size_t)onode * 128 + col] = h;
                }
            }
        }
    }
}

// Fused node-update kernel: blocks [0,512) GW head, [512,672) SW head,
// [672,896) PFAS.  LDS = 51200 B -> 3 blocks/CU.
__global__ void __launch_bounds__(256)
node_mfma(const unsigned short* __restrict__ x16,
          const unsigned short* __restrict__ meanAll,
          const float* __restrict__ Wl_pg, const float* __restrict__ Wr_pg,
          const float* __restrict__ b_pg,
          const float* __restrict__ Wl_ps, const float* __restrict__ Wr_ps,
          const float* __restrict__ b_ps,
          const float* __restrict__ Wl_gp, const float* __restrict__ Wr_gp,
          const float* __restrict__ b_gp,
          const float* __restrict__ Wl_sp, const float* __restrict__ Wr_sp,
          const float* __restrict__ b_sp,
          const float* __restrict__ W_lin, const float* __restrict__ b_lin,
          const float* __restrict__ alpha,
          float* __restrict__ out_gw, float* __restrict__ out_sw,
          float* __restrict__ out_pfas)
{
    __shared__ __align__(16) unsigned short smem[25600];   // 51200 B union
    int bx = blockIdx.x;
    if (bx < 512) {
        head_body(x16 + (size_t)20000 * 64, meanAll + (size_t)BASE_GW * 64,
                  Wl_pg, Wr_pg, b_pg, W_lin, b_lin, alpha,
                  out_gw, N_GW, bx, 512, smem);
    } else if (bx < 672) {
        head_body(x16 + (size_t)120000 * 64, meanAll + (size_t)BASE_PS * 64,
                  Wl_ps, Wr_ps, b_ps, W_lin, b_lin, alpha,
                  out_sw, N_SW, bx - 512, 160, smem);
    } else {
        pfas_body(x16, meanAll + (size_t)BASE_GP * 64, meanAll + (size_t)BASE_SP * 64,
                  Wl_gp, Wr_gp, b_gp, Wl_sp, Wr_sp, b_sp,
                  out_pfas, N_PFAS, bx - 672, 224, smem);
    }
}

extern "C" void kernel_launch(void* const* d_in, const int* in_sizes, int n_in,
                              void* d_out, int out_size, void* d_ws, size_t ws_size,
                              hipStream_t stream)
{
    const float* x_pfas = (const float*)d_in[0];
    const float* x_gw   = (const float*)d_in[1];
    const float* x_sw   = (const float*)d_in[2];
    const int* pg_src = (const int*)d_in[3];
    const int* pg_dst = (const int*)d_in[4];
    const int* gp_src = (const int*)d_in[5];
    const int* gp_dst = (const int*)d_in[6];
    const int* sp_src = (const int*)d_in[7];
    const int* sp_dst = (const int*)d_in[8];
    const int* ps_src = (const int*)d_in[9];
    const int* ps_dst = (const int*)d_in[10];
    const float* Wl_pg = (const float*)d_in[11];
    const float* Wr_pg = (const float*)d_in[12];
    const float* b_pg  = (const float*)d_in[13];
    const float* Wl_gp = (const float*)d_in[14];
    const float* Wr_gp = (const float*)d_in[15];
    const float* b_gp  = (const float*)d_in[16];
    const float* Wl_sp = (const float*)d_in[17];
    const float* Wr_sp = (const float*)d_in[18];
    const float* b_sp  = (const float*)d_in[19];
    const float* Wl_ps = (const float*)d_in[20];
    const float* Wr_ps = (const float*)d_in[21];
    const float* b_ps  = (const float*)d_in[22];
    const float* W_lin = (const float*)d_in[23];
    const float* b_lin = (const float*)d_in[24];
    const float* alpha = (const float*)d_in[25];

    float* out = (float*)d_out;
    float* out_pfas = out;                                 // 20000*128
    float* out_gw   = out + (size_t)N_PFAS * 128;          // 100000
    float* out_sw   = out_gw + N_GW;                       // 20000

    int E_PG = in_sizes[3];
    int E_GP = in_sizes[5];
    int E_SP = in_sizes[7];
    int E_PS = in_sizes[9];
    int E_total = E_PG + E_GP + E_SP + E_PS;               // 4,000,000

    // Workspace layout (~73.7 MB with transposed metadata; guarded):
    unsigned short* meanAll = (unsigned short*)d_ws;       // 160000*64 bf16 = 20.48 MB
    int* countMat  = (int*)(meanAll + (size_t)N_SEG * 64); // 512*1250 ints = 2.56 MB
    int* lofs      = countMat + NB_FILL * NBIN;            // 512*1250 ints = 2.56 MB
    int* edge_binned = lofs + NB_FILL * NBIN;              // 4,000,000 ints (16 MB)
    unsigned short* x16 = (unsigned short*)(edge_binned + E_total);  // 17.92 MB
    unsigned int* x8 = (unsigned int*)(x16 + (size_t)N_XROW * 64);   // 8.96 MB
    int* cmT = (int*)(x8 + (size_t)N_XROW * 16);           // 2.56 MB (bin-major)
    int* lfT = cmT + NB_FILL * NBIN;                       // 2.56 MB (bin-major)
    size_t needT = (size_t)((char*)(lfT + NB_FILL * NBIN) - (char*)d_ws);
    bool useT = (ws_size >= needT);

    count_cast<<<NB_FILL, 1024, 0, stream>>>(pg_dst, E_PG, gp_dst, E_GP,
                                             sp_dst, E_SP, ps_dst, E_PS,
                                             x_pfas, x_gw, x_sw, x16, x8,
                                             countMat);

    fill_stage<<<NB_FILL, 1024, 0, stream>>>(pg_src, pg_dst, E_PG,
                                             gp_src, gp_dst, E_GP,
                                             sp_src, sp_dst, E_SP,
                                             ps_src, ps_dst, E_PS,
                                             countMat, lofs, edge_binned);

    if (useT) {
        transp<<<dim3(40, 16), 1024, 0, stream>>>(countMat, lofs, cmT, lfT);
        sort_agg<<<NBIN, 1024, 0, stream>>>(cmT, lfT, 1, NB_FILL,
                                            edge_binned, x8, meanAll, E_total);
    } else {
        sort_agg<<<NBIN, 1024, 0, stream>>>(countMat, lofs, NBIN, 1,
                                            edge_binned, x8, meanAll, E_total);
    }

    node_mfma<<<896, 256, 0, stream>>>(x16, meanAll,
                                       Wl_pg, Wr_pg, b_pg,
                                       Wl_ps, Wr_ps, b_ps,
                                       Wl_gp, Wr_gp, b_gp,
                                       Wl_sp, Wr_sp, b_sp,
                                       W_lin, b_lin, alpha,
                                       out_gw, out_sw, out_pfas);
}

// Round 11
// 258.283 us; speedup vs baseline: 1.1508x; 1.0328x over previous
//
#include <hip/hip_runtime.h>
#include <hip/hip_bf16.h>

// Problem constants (from reference)
#define N_PFAS 20000
#define N_GW   100000
#define N_SW   20000
#define N_SEG  160000          // GW[0,100k) GP[100k,120k) SP[120k,140k) PS[140k,160k)
#define BASE_GW 0
#define BASE_GP 100000
#define BASE_SP 120000
#define BASE_PS 140000
#define NBIN 1250              // 160000 / 128 exactly (bin = 128 dst nodes)
#define NB_FILL 512            // chunk count (prep blocks)
#define SORT_CAP 12288         // sort_agg LDS staging (max real bin ~10.3k)
#define STAGE_CAP 8192         // prep per-chunk LDS (CH = 7813)
#define N_XROW 140000          // xp 20000 | xg 100000 | xs 20000 packed rows

typedef __attribute__((ext_vector_type(8))) short short8;   // 8 bf16 (4 VGPRs)
typedef __attribute__((ext_vector_type(4))) float f32x4;    // MFMA C/D frag
typedef __attribute__((ext_vector_type(2))) float f32x2;

__device__ __forceinline__ unsigned short f2bf(float f) {
    union { float f; unsigned int u; } v;
    v.f = f;
    unsigned int u = v.u;
    unsigned int r = (u + 0x7fffu + ((u >> 16) & 1u)) >> 16;  // RNE
    return (unsigned short)r;
}

// ---- fp8 encode/decode: HW e4m3 converters if available, else e5m2 ----
#if __has_builtin(__builtin_amdgcn_cvt_pk_f32_fp8) && __has_builtin(__builtin_amdgcn_cvt_pk_fp8_f32)
#define FP8_HW 1
__device__ __forceinline__ unsigned int enc_fp8x4(float4 v) {
    int r = __builtin_amdgcn_cvt_pk_fp8_f32(v.x, v.y, 0, false);
    r = __builtin_amdgcn_cvt_pk_fp8_f32(v.z, v.w, r, true);
    return (unsigned int)r;
}
__device__ __forceinline__ void dec_fp8x4v(unsigned int u, f32x2& lo, f32x2& hi) {
    lo = __builtin_amdgcn_cvt_pk_f32_fp8(u, false);
    hi = __builtin_amdgcn_cvt_pk_f32_fp8(u, true);
}
#else
// e5m2 = top byte of IEEE f16. Encode: f32->f16 (RNE) then RNE-round top byte.
__device__ __forceinline__ unsigned char enc1_e5m2(float f) {
    union { unsigned short u; _Float16 h; } cv;
    cv.h = (_Float16)f;
    unsigned int u = cv.u;
    unsigned int r = (u + 0x7Fu + ((u >> 8) & 1u)) >> 8;
    return (unsigned char)(r > 255u ? 255u : r);
}
__device__ __forceinline__ unsigned int enc_fp8x4(float4 v) {
    return (unsigned int)enc1_e5m2(v.x) | ((unsigned int)enc1_e5m2(v.y) << 8)
         | ((unsigned int)enc1_e5m2(v.z) << 16) | ((unsigned int)enc1_e5m2(v.w) << 24);
}
__device__ __forceinline__ float dec1_e5m2(unsigned int b) {
    union { unsigned short u; _Float16 h; } cv;
    cv.u = (unsigned short)(b << 8);
    return (float)cv.h;
}
__device__ __forceinline__ void dec_fp8x4v(unsigned int u, f32x2& lo, f32x2& hi) {
    lo.x = dec1_e5m2(u & 0xFF); lo.y = dec1_e5m2((u >> 8) & 0xFF);
    hi.x = dec1_e5m2((u >> 16) & 0xFF); hi.y = dec1_e5m2(u >> 24);
}
#endif

// Per-edge lookup helper: concatenated index -> (global seg id, src)
__device__ __forceinline__ void edge_lookup(int i,
    const int* __restrict__ s0, const int* __restrict__ d0, int E0,
    const int* __restrict__ s1, const int* __restrict__ d1, int E1,
    const int* __restrict__ s2, const int* __restrict__ d2, int E2,
    const int* __restrict__ s3, const int* __restrict__ d3,
    int& g, int& sv)
{
    if (i < E0)                { g = BASE_GW + d0[i];                 sv = s0 ? s0[i] : 0; }
    else if (i < E0 + E1)      { int j = i - E0;           g = BASE_GP + d1[j]; sv = s1 ? s1[j] : 0; }
    else if (i < E0 + E1 + E2) { int j = i - E0 - E1;      g = BASE_SP + d2[j]; sv = s2 ? s2[j] : 0; }
    else                       { int j = i - E0 - E1 - E2; g = BASE_PS + d3[j]; sv = s3 ? s3[j] : 0; }
}

// ---------------------------------------------------------------------------
// Phase 1+2+3 FUSED "prep" (count_cast + scan + fill_stage): lofs[k][*] is an
// exclusive scan of countMat[k][*] — purely chunk-local — so one block can
// histogram, scan, and scatter its own chunk in a single kernel. Saves: a
// second pass over the dst arrays, the countMat round-trip, and a launch.
//   1. cast features to bf16 + fp8 rows (grid-stride over all rows)
//   2. LDS histogram of OWN chunk over 1250 bins (4-way sub-histograms)
//   3. row-sum -> countMat row (coalesced) -> LDS scan -> lofs row + cursors
//   4. re-read own chunk (L2-hot), scatter into LDS stage, coalesced flush
// eb layout: chunk-major; bin b's edges of chunk k at [k*CH + lofs[k][b]).
// Scattered global writes are avoided throughout (R1/R6: ~16x amplification).
// LDS: 32KB union (hist | stage) + 8KB scanb + 5KB cur = ~46 KB -> 3 blk/CU.
// ---------------------------------------------------------------------------
__global__ void __launch_bounds__(1024)
prep(const int* __restrict__ s0, const int* __restrict__ d0, int E0,
     const int* __restrict__ s1, const int* __restrict__ d1, int E1,
     const int* __restrict__ s2, const int* __restrict__ d2, int E2,
     const int* __restrict__ s3, const int* __restrict__ d3, int E3,
     const float* __restrict__ xp, const float* __restrict__ xg,
     const float* __restrict__ xs, unsigned short* __restrict__ x16,
     unsigned int* __restrict__ x8,
     int* __restrict__ countMat, int* __restrict__ lofs, int* __restrict__ eb)
{
    __shared__ __align__(16) int ubuf[STAGE_CAP];  // 32 KB: h[4][NBIN] then stage
    __shared__ int scanb[2048];                    // 8 KB
    __shared__ int cur[NBIN];                      // 5 KB
    int k = blockIdx.x;
    int t = threadIdx.x;

    // Phase 1: cast features (grid-stride over whole feature set)
    const int T0 = 20000 * 16, T1 = 120000 * 16, TT = N_XROW * 16;  // float4 units
    for (int i = k * 1024 + t; i < TT; i += NB_FILL * 1024) {
        float4 v;
        if (i < T0)      v = ((const float4*)xp)[i];
        else if (i < T1) v = ((const float4*)xg)[i - T0];
        else             v = ((const float4*)xs)[i - T1];
        ushort4 o;
        o.x = f2bf(v.x); o.y = f2bf(v.y); o.z = f2bf(v.z); o.w = f2bf(v.w);
        ((ushort4*)x16)[i] = o;
        x8[i] = enc_fp8x4(v);
    }

    // Phase 2: histogram own chunk (dst only) into 4-way sub-histograms
    int (*h)[NBIN] = reinterpret_cast<int(*)[NBIN]>(ubuf);
    for (int i = t; i < NBIN; i += 1024) {
        h[0][i] = 0; h[1][i] = 0; h[2][i] = 0; h[3][i] = 0;
    }
    __syncthreads();
    int sub = t & 3;
    int total = E0 + E1 + E2 + E3;
    int CH = (total + NB_FILL - 1) / NB_FILL;
    int s = k * CH;
    int e = s + CH; if (e > total) e = total;
    for (int i0 = s + t * 4; i0 < e; i0 += 1024 * 4) {
        int gs[4];
        int m = e - i0; if (m > 4) m = 4;
        #pragma unroll
        for (int u = 0; u < 4; u++) {
            if (u < m) {
                int g, sv;
                edge_lookup(i0 + u, nullptr, d0, E0, nullptr, d1, E1,
                            nullptr, d2, E2, nullptr, d3, g, sv);
                gs[u] = g;
            }
        }
        #pragma unroll
        for (int u = 0; u < 4; u++)
            if (u < m) atomicAdd(&h[sub][gs[u] >> 7], 1);
    }
    __syncthreads();

    // Phase 3: row-sum -> countMat (coalesced) -> scan -> lofs + cursors
    int v0 = 0, v1 = 0;
    if (t < NBIN) {
        v0 = h[0][t] + h[1][t] + h[2][t] + h[3][t];
        countMat[k * NBIN + t] = v0;
    }
    if (t + 1024 < NBIN) {
        v1 = h[0][t + 1024] + h[1][t + 1024] + h[2][t + 1024] + h[3][t + 1024];
        countMat[k * NBIN + t + 1024] = v1;
    }
    scanb[t] = v0; scanb[t + 1024] = v1;
    __syncthreads();
    #pragma unroll
    for (int off = 1; off < 2048; off <<= 1) {
        int a = (t >= off) ? scanb[t - off] : 0;
        int b2 = (t + 1024 >= off) ? scanb[t + 1024 - off] : 0;
        __syncthreads();
        scanb[t] += a; scanb[t + 1024] += b2;
        __syncthreads();
    }
    if (t < NBIN)        { int ex = scanb[t] - v0;        cur[t] = ex;        lofs[k * NBIN + t] = ex; }
    if (t + 1024 < NBIN) { int ex = scanb[t + 1024] - v1; cur[t + 1024] = ex; lofs[k * NBIN + t + 1024] = ex; }
    __syncthreads();   // h (ubuf) reads complete -> safe to reuse as stage

    // Phase 4: scatter own chunk (src+dst; dst re-read is L2-hot) into stage
    int* stage = ubuf;
    for (int i0 = s + t * 4; i0 < e; i0 += 1024 * 4) {
        int g[4], sv[4];
        int m = e - i0; if (m > 4) m = 4;
        #pragma unroll
        for (int u = 0; u < 4; u++)
            if (u < m) edge_lookup(i0 + u, s0, d0, E0, s1, d1, E1,
                                   s2, d2, E2, s3, d3, g[u], sv[u]);
        #pragma unroll
        for (int u = 0; u < 4; u++) {
            if (u < m) {
                int slot = atomicAdd(&cur[g[u] >> 7], 1);
                stage[slot] = sv[u] | ((g[u] & 127) << 20);
            }
        }
    }
    __syncthreads();
    int n = e - s;
    for (int i = t; i < n; i += 1024) eb[s + i] = stage[i];
}

// ---------------------------------------------------------------------------
// Phase 2b: tiled transpose of countMat/lofs (512x1250 -> 1250x512) so
// sort_agg's per-bin metadata reads are CONTIGUOUS 2KB loads instead of
// 512 x 4B column-strided reads (validated R8: FETCH 134 -> 92 MB).
// ---------------------------------------------------------------------------
__global__ void __launch_bounds__(1024)
transp(const int* __restrict__ cm, const int* __restrict__ lf,
       int* __restrict__ cmT, int* __restrict__ lfT)
{
    __shared__ int t0[32][33], t1[32][33];
    int tx = threadIdx.x & 31, ty = threadIdx.x >> 5;
    int c = blockIdx.x * 32 + tx;         // bin
    int r = blockIdx.y * 32 + ty;         // chunk (<512 always)
    if (c < NBIN) {
        t0[ty][tx] = cm[r * NBIN + c];
        t1[ty][tx] = lf[r * NBIN + c];
    }
    __syncthreads();
    int c2 = blockIdx.x * 32 + ty;        // bin (output row)
    int r2 = blockIdx.y * 32 + tx;        // chunk (output col)
    if (c2 < NBIN) {
        cmT[c2 * NB_FILL + r2] = t0[tx][ty];
        lfT[c2 * NB_FILL + r2] = t1[tx][ty];
    }
}

// ---------------------------------------------------------------------------
// Phase 3+4 FUSED: STATIC bin assignment b=(blockIdx+781)%NBIN (GP-heavy
// bins first, spread across ALL XCDs — R8 proved XCD-partitioned queues
// destroy load balance & request concurrency: 79->107us). Compacted
// coalesced run assembly (binary search over cposS), pass 2 LDS-only perm
// scatter, proven 2-nodes-per-wave fp8 agg.
// cm/lf accessed via runtime strides: transposed (sA=1,sB=512) when ws
// allows, else row-major (sA=NBIN,sB=1).
// ---------------------------------------------------------------------------
__global__ void __launch_bounds__(1024)
sort_agg(const int* __restrict__ cm, const int* __restrict__ lf,
         int sA, int sB,
         const int* __restrict__ eb, const unsigned int* __restrict__ x8,
         unsigned short* __restrict__ meanAll, int E_total)
{
    __shared__ int stage[SORT_CAP];            // 48 KB — words in COMPACTED order
    __shared__ unsigned short perm[SORT_CAP];  // 24 KB — sorted pos -> compacted idx
    __shared__ int rs[NB_FILL];                // run start (global index) per chunk
    __shared__ int cposS[NB_FILL + 1];         // compacted prefix of run lengths
    __shared__ int cnt[128], basep[128], cur[128], lstart[128];
    int lane = threadIdx.x & 63;
    int t = threadIdx.x;
    int b = (int)((blockIdx.x + 781u) % NBIN);   // GP-heavy bins first
    int CH = (E_total + NB_FILL - 1) / NB_FILL;

    if (t < 128) cnt[t] = 0;
    if (t < NB_FILL) {
        int ckv = cm[t * sA + b * sB];
        rs[t] = t * CH + lf[t * sA + b * sB];
        cposS[t + 1] = ckv;
    }
    if (t == 0) cposS[0] = 0;
    __syncthreads();
    // inclusive scan of cposS[1..512] (Hillis-Steele over 512)
    #pragma unroll
    for (int off = 1; off < NB_FILL; off <<= 1) {
        int v = 0;
        if (t < NB_FILL && t >= off) v = cposS[t + 1 - off];
        __syncthreads();
        if (t < NB_FILL) cposS[t + 1] += v;
        __syncthreads();
    }
    int n = cposS[NB_FILL];
    if (n > SORT_CAP) n = SORT_CAP;       // statistically unreachable (20 sigma)

    // Pass 1: compacted coalesced read; resolve rb; store word; count degrees.
    for (int i = t; i < n; i += 1024) {
        int lo = 0, hi = NB_FILL;
        #pragma unroll
        for (int it = 0; it < 9; it++) {   // 2^9 = 512
            int mid = (lo + hi) >> 1;
            if (cposS[mid] <= i) lo = mid; else hi = mid;
        }
        int w = eb[rs[lo] + i - cposS[lo]];
        int dl = w >> 20;
        int g = (b << 7) + dl;
        int rb = (g < BASE_GP) ? 0 : (g < BASE_SP) ? 20000
               : (g < BASE_PS) ? 120000 : 0;
        stage[i] = ((w & 0xFFFFF) + rb) | (dl << 20);   // row id (<2^20) | node
        atomicAdd(&cnt[dl], 1);
    }
    __syncthreads();
    if (t < 128) basep[t] = cnt[t];
    __syncthreads();
    #pragma unroll
    for (int off = 1; off < 128; off <<= 1) {
        int v = 0;
        if (t < 128 && t >= off) v = basep[t - off];
        __syncthreads();
        if (t < 128) basep[t] += v;
        __syncthreads();
    }
    if (t < 128) {
        int ex = basep[t] - cnt[t];       // exclusive
        cur[t] = ex;
        lstart[t] = ex;
    }
    __syncthreads();

    // Pass 2 (LDS-only): scatter compacted indices into sorted perm positions.
    for (int i = t; i < n; i += 1024) {
        int dl = stage[i] >> 20;
        int slot = atomicAdd(&cur[dl], 1);
        perm[slot] = (unsigned short)i;
    }
    __syncthreads();

    // Aggregate: 16 waves x 4 iterations x 2 nodes/wave = 128 nodes.
    int wv = threadIdx.x >> 6;        // 0..15
    int h  = lane >> 5;
    int eq = (lane >> 3) & 3;
    int fc = lane & 7;
    int l32 = lane & 31;
    for (int it = 0; it < 4; it++) {
        int nl = 2 * (it * 16 + wv) + h;      // local node 0..127 (per half)
        int s0 = lstart[nl];
        int c0 = cnt[nl];
        if (s0 + c0 > SORT_CAP) c0 = SORT_CAP - s0;   // unreachable guard
        f32x2 a01 = {0.f,0.f}, a23 = {0.f,0.f}, a45 = {0.f,0.f}, a67 = {0.f,0.f};
        int j = 0;
        for (; j + 32 <= c0; j += 32) {
            int ev = stage[perm[s0 + j + l32]] & 0xFFFFF;
            #pragma unroll
            for (int q = 0; q < 8; q++) {
                int id = __shfl(ev, h * 32 + 4 * q + eq);
                uint2 v = *(const uint2*)(x8 + (((size_t)id) << 4) + fc * 2);
                f32x2 lo0, hi0, lo1, hi1;
                dec_fp8x4v(v.x, lo0, hi0);
                dec_fp8x4v(v.y, lo1, hi1);
                a01 += lo0; a23 += hi0; a45 += lo1; a67 += hi1;
            }
        }
        if (j < c0) {
            int blk = c0 - j;
            int ev = (l32 < blk) ? (stage[perm[s0 + j + l32]] & 0xFFFFF) : 0;
            int ng = (blk + 3) >> 2;
            for (int q = 0; q < ng; q++) {
                int idx = 4 * q + eq;
                int id = __shfl(ev, h * 32 + idx);
                if (idx < blk) {
                    uint2 v = *(const uint2*)(x8 + (((size_t)id) << 4) + fc * 2);
                    f32x2 lo0, hi0, lo1, hi1;
                    dec_fp8x4v(v.x, lo0, hi0);
                    dec_fp8x4v(v.y, lo1, hi1);
                    a01 += lo0; a23 += hi0; a45 += lo1; a67 += hi1;
                }
            }
        }
        float f[8] = {a01.x, a01.y, a23.x, a23.y, a45.x, a45.y, a67.x, a67.y};
        #pragma unroll
        for (int r = 0; r < 8; r++) {
            f[r] += __shfl_xor(f[r], 8);
            f[r] += __shfl_xor(f[r], 16);
        }
        if (eq == 0) {
            float inv = 1.0f / (float)(c0 > 1 ? c0 : 1);
            ushort4 o0, o1;
            o0.x = f2bf(f[0] * inv); o0.y = f2bf(f[1] * inv);
            o0.z = f2bf(f[2] * inv); o0.w = f2bf(f[3] * inv);
            o1.x = f2bf(f[4] * inv); o1.y = f2bf(f[5] * inv);
            o1.z = f2bf(f[6] * inv); o1.w = f2bf(f[7] * inv);
            int gnode = (b << 7) + nl;
            ushort4* dst = (ushort4*)(meanAll + (size_t)gnode * 64 + fc * 8);
            dst[0] = o0;
            dst[1] = o1;
        }
    }
}

// ---------------------------------------------------------------------------
// Fused node-update kernel bodies. A-fragments loaded DIRECTLY from global;
// shared mem = W only; one barrier total.
// ---------------------------------------------------------------------------
__device__ __forceinline__ void
head_body(const unsigned short* __restrict__ x16r,
          const unsigned short* __restrict__ mean,
          const float* __restrict__ Wl, const float* __restrict__ Wr,
          const float* __restrict__ b, const float* __restrict__ Wlin,
          const float* __restrict__ b_lin, const float* __restrict__ alpha,
          float* __restrict__ out, int N, int bid, int nblocks,
          unsigned short* __restrict__ smem)
{
    unsigned short* sW = smem;            // [128][136]

    for (int i = threadIdx.x; i < 64 * 128; i += 256) {
        int k = i >> 7, col = i & 127;
        sW[col * 136 + k]      = f2bf(Wl[k * 128 + col]);
        sW[col * 136 + 64 + k] = f2bf(Wr[k * 128 + col]);
    }

    int lane = threadIdx.x & 63;
    int wid  = threadIdx.x >> 6;
    int c    = lane & 15;
    int quad = lane >> 4;
    float wl_c[8], b_c[8];
    #pragma unroll
    for (int t = 0; t < 8; t++) {
        wl_c[t] = Wlin[t * 16 + c];
        b_c[t]  = b[t * 16 + c];
    }
    float blin = b_lin[0], al = alpha[0];
    __syncthreads();   // sW ready; no further barriers

    int ntiles = (N + 63) >> 6;
    for (int tile = bid; tile < ntiles; tile += nblocks) {
        int base = tile << 6;
        int node = base + wid * 16 + c;       // A-row this lane reads
        bool valid = node < N;
        const unsigned short* mrow = mean + (size_t)node * 64;
        const unsigned short* xrow = x16r + (size_t)node * 64;

        f32x4 acc[8] = {};
        #pragma unroll
        for (int step = 0; step < 4; step++) {
            short8 a = {};
            if (valid) {
                const unsigned short* src = (step < 2)
                    ? (mrow + step * 32 + quad * 8)
                    : (xrow + (step - 2) * 32 + quad * 8);
                a = *(const short8*)src;
            }
            #pragma unroll
            for (int t = 0; t < 8; t++) {
                short8 bb = *(const short8*)&sW[(t * 16 + c) * 136 + step * 32 + quad * 8];
                acc[t] = __builtin_amdgcn_mfma_f32_16x16x32_bf16(a, bb, acc[t], 0, 0, 0);
            }
        }

        float p[4] = {0.f, 0.f, 0.f, 0.f};
        #pragma unroll
        for (int t = 0; t < 8; t++) {
            #pragma unroll
            for (int r = 0; r < 4; r++) {
                float h = fmaxf(acc[t][r] + b_c[t], 0.0f);
                p[r] += h * wl_c[t];
            }
        }
        #pragma unroll
        for (int m = 1; m < 16; m <<= 1) {
            #pragma unroll
            for (int r = 0; r < 4; r++) p[r] += __shfl_xor(p[r], m);
        }
        if (c == 0) {
            #pragma unroll
            for (int r = 0; r < 4; r++) {
                int onode = base + wid * 16 + quad * 4 + r;
                if (onode < N) {
                    float y = p[r] + blin;
                    out[onode] = y > 0.0f ? y : al * y;
                }
            }
        }
    }
}

__device__ __forceinline__ void
pfas_body(const unsigned short* __restrict__ x16p,
          const unsigned short* __restrict__ meanGP,
          const unsigned short* __restrict__ meanSP,
          const float* __restrict__ WlGP, const float* __restrict__ WrGP,
          const float* __restrict__ bGP,
          const float* __restrict__ WlSP, const float* __restrict__ WrSP,
          const float* __restrict__ bSP,
          float* __restrict__ out, int N, int bid, int nblocks,
          unsigned short* __restrict__ smem)
{
    unsigned short* sW = smem;            // [128][200]

    for (int i = threadIdx.x; i < 64 * 128; i += 256) {
        int k = i >> 7, col = i & 127;
        sW[col * 200 + k]       = f2bf(WlGP[k * 128 + col]);
        sW[col * 200 + 64 + k]  = f2bf(WlSP[k * 128 + col]);
        sW[col * 200 + 128 + k] = f2bf(WrGP[k * 128 + col] + WrSP[k * 128 + col]);
    }

    int lane = threadIdx.x & 63;
    int wid  = threadIdx.x >> 6;
    int c    = lane & 15;
    int quad = lane >> 4;
    int rg   = (wid & 1) * 16;
    int cg   = (wid >> 1) * 4;
    float b_c[4];
    #pragma unroll
    for (int t = 0; t < 4; t++)
        b_c[t] = bGP[(cg + t) * 16 + c] + bSP[(cg + t) * 16 + c];
    __syncthreads();   // sW ready; no further barriers

    int ntiles = (N + 31) >> 5;
    for (int tile = bid; tile < ntiles; tile += nblocks) {
        int base = tile << 5;
        int node = base + rg + c;             // A-row this lane reads
        bool valid = node < N;
        const unsigned short* grow = meanGP + (size_t)node * 64;
        const unsigned short* srow = meanSP + (size_t)node * 64;
        const unsigned short* xrow = x16p + (size_t)node * 64;

        f32x4 acc[4] = {};
        #pragma unroll
        for (int step = 0; step < 6; step++) {
            short8 a = {};
            if (valid) {
                const unsigned short* src = (step < 2)
                    ? (grow + step * 32 + quad * 8)
                    : (step < 4) ? (srow + (step - 2) * 32 + quad * 8)
                                 : (xrow + (step - 4) * 32 + quad * 8);
                a = *(const short8*)src;
            }
            #pragma unroll
            for (int t = 0; t < 4; t++) {
                short8 bb = *(const short8*)&sW[((cg + t) * 16 + c) * 200 + step * 32 + quad * 8];
                acc[t] = __builtin_amdgcn_mfma_f32_16x16x32_bf16(a, bb, acc[t], 0, 0, 0);
            }
        }

        #pragma unroll
        for (int t = 0; t < 4; t++) {
            int col = (cg + t) * 16 + c;
            #pragma unroll
            for (int r = 0; r < 4; r++) {
                int onode = base + rg + quad * 4 + r;
                if (onode < N) {
                    float h = fmaxf(acc[t][r] + b_c[t], 0.0f);
                    out[(size_t)onode * 128 + col] = h;
                }
            }
        }
    }
}

// Fused node-update kernel: blocks [0,512) GW head, [512,672) SW head,
// [672,896) PFAS.  LDS = 51200 B -> 3 blocks/CU.
__global__ void __launch_bounds__(256)
node_mfma(const unsigned short* __restrict__ x16,
          const unsigned short* __restrict__ meanAll,
          const float* __restrict__ Wl_pg, const float* __restrict__ Wr_pg,
          const float* __restrict__ b_pg,
          const float* __restrict__ Wl_ps, const float* __restrict__ Wr_ps,
          const float* __restrict__ b_ps,
          const float* __restrict__ Wl_gp, const float* __restrict__ Wr_gp,
          const float* __restrict__ b_gp,
          const float* __restrict__ Wl_sp, const float* __restrict__ Wr_sp,
          const float* __restrict__ b_sp,
          const float* __restrict__ W_lin, const float* __restrict__ b_lin,
          const float* __restrict__ alpha,
          float* __restrict__ out_gw, float* __restrict__ out_sw,
          float* __restrict__ out_pfas)
{
    __shared__ __align__(16) unsigned short smem[25600];   // 51200 B union
    int bx = blockIdx.x;
    if (bx < 512) {
        head_body(x16 + (size_t)20000 * 64, meanAll + (size_t)BASE_GW * 64,
                  Wl_pg, Wr_pg, b_pg, W_lin, b_lin, alpha,
                  out_gw, N_GW, bx, 512, smem);
    } else if (bx < 672) {
        head_body(x16 + (size_t)120000 * 64, meanAll + (size_t)BASE_PS * 64,
                  Wl_ps, Wr_ps, b_ps, W_lin, b_lin, alpha,
                  out_sw, N_SW, bx - 512, 160, smem);
    } else {
        pfas_body(x16, meanAll + (size_t)BASE_GP * 64, meanAll + (size_t)BASE_SP * 64,
                  Wl_gp, Wr_gp, b_gp, Wl_sp, Wr_sp, b_sp,
                  out_pfas, N_PFAS, bx - 672, 224, smem);
    }
}

extern "C" void kernel_launch(void* const* d_in, const int* in_sizes, int n_in,
                              void* d_out, int out_size, void* d_ws, size_t ws_size,
                              hipStream_t stream)
{
    const float* x_pfas = (const float*)d_in[0];
    const float* x_gw   = (const float*)d_in[1];
    const float* x_sw   = (const float*)d_in[2];
    const int* pg_src = (const int*)d_in[3];
    const int* pg_dst = (const int*)d_in[4];
    const int* gp_src = (const int*)d_in[5];
    const int* gp_dst = (const int*)d_in[6];
    const int* sp_src = (const int*)d_in[7];
    const int* sp_dst = (const int*)d_in[8];
    const int* ps_src = (const int*)d_in[9];
    const int* ps_dst = (const int*)d_in[10];
    const float* Wl_pg = (const float*)d_in[11];
    const float* Wr_pg = (const float*)d_in[12];
    const float* b_pg  = (const float*)d_in[13];
    const float* Wl_gp = (const float*)d_in[14];
    const float* Wr_gp = (const float*)d_in[15];
    const float* b_gp  = (const float*)d_in[16];
    const float* Wl_sp = (const float*)d_in[17];
    const float* Wr_sp = (const float*)d_in[18];
    const float* b_sp  = (const float*)d_in[19];
    const float* Wl_ps = (const float*)d_in[20];
    const float* Wr_ps = (const float*)d_in[21];
    const float* b_ps  = (const float*)d_in[22];
    const float* W_lin = (const float*)d_in[23];
    const float* b_lin = (const float*)d_in[24];
    const float* alpha = (const float*)d_in[25];

    float* out = (float*)d_out;
    float* out_pfas = out;                                 // 20000*128
    float* out_gw   = out + (size_t)N_PFAS * 128;          // 100000
    float* out_sw   = out_gw + N_GW;                       // 20000

    int E_PG = in_sizes[3];
    int E_GP = in_sizes[5];
    int E_SP = in_sizes[7];
    int E_PS = in_sizes[9];
    int E_total = E_PG + E_GP + E_SP + E_PS;               // 4,000,000

    // Workspace layout (~73.7 MB with transposed metadata; guarded):
    unsigned short* meanAll = (unsigned short*)d_ws;       // 160000*64 bf16 = 20.48 MB
    int* countMat  = (int*)(meanAll + (size_t)N_SEG * 64); // 512*1250 ints = 2.56 MB
    int* lofs      = countMat + NB_FILL * NBIN;            // 512*1250 ints = 2.56 MB
    int* edge_binned = lofs + NB_FILL * NBIN;              // 4,000,000 ints (16 MB)
    unsigned short* x16 = (unsigned short*)(edge_binned + E_total);  // 17.92 MB
    unsigned int* x8 = (unsigned int*)(x16 + (size_t)N_XROW * 64);   // 8.96 MB
    int* cmT = (int*)(x8 + (size_t)N_XROW * 16);           // 2.56 MB (bin-major)
    int* lfT = cmT + NB_FILL * NBIN;                       // 2.56 MB (bin-major)
    size_t needT = (size_t)((char*)(lfT + NB_FILL * NBIN) - (char*)d_ws);
    bool useT = (ws_size >= needT);

    prep<<<NB_FILL, 1024, 0, stream>>>(pg_src, pg_dst, E_PG,
                                       gp_src, gp_dst, E_GP,
                                       sp_src, sp_dst, E_SP,
                                       ps_src, ps_dst, E_PS,
                                       x_pfas, x_gw, x_sw, x16, x8,
                                       countMat, lofs, edge_binned);

    if (useT) {
        transp<<<dim3(40, 16), 1024, 0, stream>>>(countMat, lofs, cmT, lfT);
        sort_agg<<<NBIN, 1024, 0, stream>>>(cmT, lfT, 1, NB_FILL,
                                            edge_binned, x8, meanAll, E_total);
    } else {
        sort_agg<<<NBIN, 1024, 0, stream>>>(countMat, lofs, NBIN, 1,
                                            edge_binned, x8, meanAll, E_total);
    }

    node_mfma<<<896, 256, 0, stream>>>(x16, meanAll,
                                       Wl_pg, Wr_pg, b_pg,
                                       Wl_ps, Wr_ps, b_ps,
                                       Wl_gp, Wr_gp, b_gp,
                                       Wl_sp, Wr_sp, b_sp,
                                       W_lin, b_lin, alpha,
                                       out_gw, out_sw, out_pfas);
}